// Round 8
// baseline (630.704 us; speedup 1.0000x reference)
//
#include <hip/hip_runtime.h>
#include <math.h>

#define FD     512
#define NBATCH 16
#define NROWS  16384
#define ROWS   64              // rows per block
#define NBLK   (NROWS/ROWS)    // 256 blocks = 1 per CU
#define TPB    1024            // 16 waves/block
#define MM     5
#define LAMV   1e-4f
#define MAXIT  50
#define TOLV   0.01f
#define NTOT   8388608
#define PADW   520             // LDS row stride (bf16 elems), 16B aligned

typedef __attribute__((ext_vector_type(8))) short  short8;   // 8 bf16
typedef __attribute__((ext_vector_type(4))) short  short4v;  // 4 bf16 (8B)
typedef __attribute__((ext_vector_type(4))) float  float4v;  // MFMA C/D frag

// Persistent device state; fully rewritten (or provably unused) every call.
__device__ unsigned short g_Fm[MM][NTOT];
__device__ unsigned short g_G [MM][NTOT];
__device__ unsigned short g_Wb [FD*FD];        // bf16(lin_w) row-major
__device__ unsigned short g_WbO[FD*FD];        // bf16(weight) row-major
__device__ float g_acc [MAXIT-2][NBATCH][8];   // per-iter Gram-row dots [0..4], ||f||^2 [5]
__device__ float g_acc0[NBATCH][8];            // init dots d00,d01,d11
__device__ float g_alpha[8];                   // alphas of last LIVE iteration
__device__ int   g_lastk;                      // k of last live iteration (>=2)

static __device__ __forceinline__ unsigned short f2bf(float f) {
    unsigned u = __float_as_uint(f);
    u += 0x7fff + ((u >> 16) & 1);             // RNE
    return (unsigned short)(u >> 16);
}
static __device__ __forceinline__ float bf2f(unsigned short s) {
    return __uint_as_float(((unsigned)s) << 16);
}

// 64x512 tile GEMM: D = A(64x512 bf16, LDS) @ W^T + bias, SWAPPED-OPERAND form.
// We issue mfma(W_frag, A_frag): D'[m][n] with m = W-row (output column),
// n = A-row (output row). Fragment LOADS are identical to the original
// orientation (verified layouts m89/m91: A-op [m=lane&15][k=quad*8+j],
// B-op [k=quad*8+j][n=lane&15]); only the C/D mapping changes:
//   out_row = r16*16 + (lane&15), out_col = wv*32 + ct*16 + quad*4 + reg
// so each lane holds 4 CONSECUTIVE output columns of one row -> epilogue is
// 8 vector stores (short4 LDS / float4 global) instead of 32 scalar stores.
// Bit-identical: same per-element dot products, same HW reduction tree; bias
// init places the same value per output element.
// MODE 0: bf16 -> FsOut (LDS). MODE 1: fp32 -> gout (global tile base).
template<int MODE>
static __device__ __forceinline__ void mfma_gemm(const unsigned short* __restrict__ Wb,
                                                 const float* __restrict__ bvec,
                                                 const unsigned short* AsIn,
                                                 unsigned short* FsOut,
                                                 float* __restrict__ gout)
{
    const int lane = threadIdx.x & 63;
    const int wv   = threadIdx.x >> 6;     // 0..15
    const int lm   = lane & 15;
    const int quad = lane >> 4;
    float4v acc[4][2];
#pragma unroll
    for (int ct = 0; ct < 2; ct++) {
        const int c0 = wv*32 + ct*16 + quad*4;
#pragma unroll
        for (int r = 0; r < 4; r++) {
            const float b = bvec[c0 + r];
#pragma unroll
            for (int r16 = 0; r16 < 4; r16++) acc[r16][ct][r] = b;
        }
    }
#pragma unroll
    for (int q = 0; q < 4; q++) {
#pragma unroll
        for (int kb = 0; kb < 4; kb++) {
            const int ko = q*128 + kb*32 + quad*8;
            short8 bf[2];
#pragma unroll
            for (int ct = 0; ct < 2; ct++)
                bf[ct] = *(const short8*)(Wb + (wv*32 + ct*16 + lm)*FD + ko);
            short8 af[4];
#pragma unroll
            for (int r16 = 0; r16 < 4; r16++)
                af[r16] = *(const short8*)(AsIn + (r16*16 + lm)*PADW + ko);
#pragma unroll
            for (int r16 = 0; r16 < 4; r16++) {
                acc[r16][0] = __builtin_amdgcn_mfma_f32_16x16x32_bf16(bf[0], af[r16], acc[r16][0], 0,0,0);
                acc[r16][1] = __builtin_amdgcn_mfma_f32_16x16x32_bf16(bf[1], af[r16], acc[r16][1], 0,0,0);
            }
        }
    }
#pragma unroll
    for (int ct = 0; ct < 2; ct++) {
        const int c0 = wv*32 + ct*16 + quad*4;
#pragma unroll
        for (int r16 = 0; r16 < 4; r16++) {
            const int row = r16*16 + lm;
            if (MODE == 0) {
                short4v v;
#pragma unroll
                for (int r = 0; r < 4; r++) v[r] = (short)f2bf(acc[r16][ct][r]);
                *(short4v*)(FsOut + row*PADW + c0) = v;
            } else {
                float4 v;
                v.x = acc[r16][ct][0]; v.y = acc[r16][ct][1];
                v.z = acc[r16][ct][2]; v.w = acc[r16][ct][3];
                *(float4*)(gout + row*FD + c0) = v;
            }
        }
    }
}

static __device__ __forceinline__ void red6(const float vals[6], float (*redS)[8], float* accrow)
{
    const int lane = threadIdx.x & 63, wv = threadIdx.x >> 6;   // wv 0..15
#pragma unroll
    for (int j = 0; j < 6; j++) {
        float v = vals[j];
#pragma unroll
        for (int o = 32; o; o >>= 1) v += __shfl_down(v, o);
        if (lane == 0) redS[wv][j] = v;
    }
    __syncthreads();
    if (threadIdx.x < 6) {
        float s = 0.f;
#pragma unroll
        for (int w = 0; w < 16; w++) s += redS[w][threadIdx.x];
        atomicAdd(accrow + threadIdx.x, s);   // device-scope
    }
}

// ---------------- init0: weight bf16 conversion + zero accumulators ----------
__global__ void __launch_bounds__(256) k_init0(const float* __restrict__ lin_w,
                                               const float* __restrict__ weight)
{
    const int i0 = blockIdx.x*256 + threadIdx.x, stride = gridDim.x*256;
    for (int i = i0; i < FD*FD; i += stride) {
        g_Wb [i] = f2bf(lin_w[i]);
        g_WbO[i] = f2bf(weight[i]);
    }
    float* a = &g_acc[0][0][0];
    for (int i = i0; i < (MAXIT-2)*NBATCH*8; i += stride) a[i] = 0.f;
    float* a0 = &g_acc0[0][0];
    for (int i = i0; i < NBATCH*8; i += stride) a0[i] = 0.f;
}

// ---------------- init1: F0=f(x~0), F1=f(F~0), G0, G1, init Gram dots --------
__global__ void __launch_bounds__(TPB, 4) k_init1(const float* __restrict__ x,
                                                  const float* __restrict__ lin_b)
{
    __shared__ __align__(16) unsigned short As[ROWS*PADW];
    __shared__ __align__(16) unsigned short Fs[ROWS*PADW];
    __shared__ float redS[16][8];
    const int tid = threadIdx.x;
    const int t = blockIdx.x, b = t >> 4;
    const int base = t * (ROWS*FD);

#pragma unroll
    for (int i = 0; i < 4; i++) {               // bf16(x0 tile) -> As
        const int e = (i*TPB + tid) * 8;
        const float4 a0 = *(const float4*)(x + base + e);
        const float4 a1 = *(const float4*)(x + base + e + 4);
        short8 v;
        v[0]=f2bf(a0.x); v[1]=f2bf(a0.y); v[2]=f2bf(a0.z); v[3]=f2bf(a0.w);
        v[4]=f2bf(a1.x); v[5]=f2bf(a1.y); v[6]=f2bf(a1.z); v[7]=f2bf(a1.w);
        *(short8*)(As + (e>>9)*PADW + (e&511)) = v;
    }
    __syncthreads();
    mfma_gemm<0>(g_Wb, lin_b, As, Fs, nullptr);   // Fs = bf16(f(x~0))
    __syncthreads();
    float d00 = 0.f;
#pragma unroll
    for (int i = 0; i < 4; i++) {
        const int e = (i*TPB + tid) * 8;
        const int off = base + e, lo = (e>>9)*PADW + (e&511);
        const short8 fv = *(const short8*)(Fs + lo);
        const short8 xv = *(const short8*)(As + lo);
        short8 gv;
#pragma unroll
        for (int j = 0; j < 8; j++) {
            const float g = bf2f((unsigned short)fv[j]) - bf2f((unsigned short)xv[j]);
            gv[j] = (short)f2bf(g);
            d00 = fmaf(g, g, d00);
        }
        *(short8*)(&g_Fm[0][off]) = fv;
        *(short8*)(&g_G [0][off]) = gv;
    }
    __syncthreads();
    mfma_gemm<0>(g_Wb, lin_b, Fs, As, nullptr);   // As = bf16(f(F~0))
    __syncthreads();
    float d01 = 0.f, d11 = 0.f;
#pragma unroll
    for (int i = 0; i < 4; i++) {
        const int e = (i*TPB + tid) * 8;
        const int off = base + e, lo = (e>>9)*PADW + (e&511);
        const short8 f1 = *(const short8*)(As + lo);
        const short8 f0 = *(const short8*)(Fs + lo);
        const short8 g0 = *(const short8*)(&g_G[0][off]);
        short8 gv;
#pragma unroll
        for (int j = 0; j < 8; j++) {
            const float g = bf2f((unsigned short)f1[j]) - bf2f((unsigned short)f0[j]);
            gv[j] = (short)f2bf(g);
            d11 = fmaf(g, g, d11);
            d01 = fmaf(bf2f((unsigned short)g0[j]), g, d01);
        }
        *(short8*)(&g_Fm[1][off]) = f1;
        *(short8*)(&g_G [1][off]) = gv;
    }
    const float vals[6] = {d00, d01, d11, 0.f, 0.f, 0.f};
    red6(vals, redS, &g_acc0[b][0]);
}

// ---------------- one Anderson iteration (k = 2..49) -------------------------
__global__ void __launch_bounds__(TPB, 4) k_iter(const float* __restrict__ lin_b, int k)
{
    __shared__ __align__(16) unsigned short As[ROWS*PADW];
    __shared__ __align__(16) unsigned short Fs[ROWS*PADW];
    __shared__ float gramS[MM][MM];
    __shared__ float alphaS[MM];
    __shared__ float Hs[48];
    __shared__ float redS[16][8];
    __shared__ float gAs[MM][MM];   // Gram window cache (wave-1 parallel load)
    __shared__ float ga0S[3];       // d00,d01,d11
    __shared__ float sres;

    const int tid = threadIdx.x;
    const int t = blockIdx.x, b = t >> 4;
    const int base = t * (ROWS*FD);
    const int it = k - 2, idx = k % MM, nk = (k < MM) ? k : MM;
    const int j0 = (k - 5 > 2) ? (k - 5) : 2;

    // wave 0: residual of iteration k-1 (skipped iterations leave zeros)
    if (k > 2 && (tid >> 6) == 0) {
        float v = 0.f;
        if (tid < 32) {
            const int bb = tid & 15;
            const int jj = (tid < 16) ? ((k-1) % MM) : 5;
            v = g_acc[it-1][bb][jj];
        }
        v += __shfl_xor(v, 1); v += __shfl_xor(v, 2);
        v += __shfl_xor(v, 4); v += __shfl_xor(v, 8);
        const float num = __shfl(v, 0), den = __shfl(v, 16);
        if (tid == 0) sres = sqrtf(num) / (1e-5f + sqrtf(den));
    }
    // wave 1: Gram window + init dots -> LDS (kills ~25 serialized lane-0 loads)
    if ((tid >> 6) == 1) {
        const int l = tid & 63;
        if (l < 25) {
            const int jj = j0 + l/5;
            if (jj < k) gAs[l/5][l%5] = g_acc[jj-2][b][l%5];
        } else if (l < 28) {
            ga0S[l-25] = g_acc0[b][l-25];
        }
    }
    __syncthreads();
    if (k > 2 && sres < TOLV) return;            // uniform across grid
    // NOTE: dead launches (post-convergence) return HERE with only the tiny
    // residual/Gram loads in flight (~2.5 us). The Fm prefetch below must stay
    // AFTER this gate: issuing it pre-gate cost ~40 MB x ~35 dead launches
    // (round-5 regression, 794 us vs 630).

    // Prefetch pass-1 Fm reads, chunks 0-1 (own tile). Issued by all waves
    // before lane 0's serial solve, so the ~2-4 us solve hides the latency.
    short8 pf0[MM], pf1[MM];
#pragma unroll
    for (int m = 0; m < MM; m++) if (m < nk) {
        pf0[m] = *(const short8*)(&g_Fm[m][base + (0*TPB + tid)*8]);
        pf1[m] = *(const short8*)(&g_Fm[m][base + (1*TPB + tid)*8]);
    }
    __builtin_amdgcn_sched_barrier(0);           // keep loads above the solve

    // --- Gram replay (chronological, last <=5 iterations) + bordered 6x6 solve
    if (tid == 0) {
#pragma unroll
        for (int i = 0; i < MM; i++)
#pragma unroll
            for (int j = 0; j < MM; j++) gramS[i][j] = 0.f;
        gramS[0][0] = ga0S[0];
        gramS[0][1] = gramS[1][0] = ga0S[1];
        gramS[1][1] = ga0S[2];
        for (int j = j0; j < k; j++) {
            const int ij = j % MM, nkj = (j < MM) ? j : MM;
            for (int c = 0; c < MM; c++)
                if (c < nkj || c == ij) {
                    const float vv = gAs[j - j0][c];
                    gramS[ij][c] = vv; gramS[c][ij] = vv;
                }
        }
        float* H = Hs;                            // 6x7 augmented
        for (int i = 0; i < 42; i++) H[i] = 0.f;
        for (int j = 0; j < nk; j++) { H[1+j] = 1.f; H[(1+j)*7] = 1.f; }
#pragma unroll
        for (int i = 0; i < MM; i++) H[(1+i)*7 + (1+i)] = LAMV;
        for (int i = 0; i < nk; i++)
            for (int j = 0; j < nk; j++)
                H[(1+i)*7 + (1+j)] = gramS[i][j] + (i == j ? LAMV : 0.f);
        H[6] = 1.f;                               // rhs = e0
        for (int col = 0; col < 6; col++) {
            int p = col; float mx = fabsf(H[col*7+col]);
            for (int r2 = col+1; r2 < 6; r2++) {
                const float vv = fabsf(H[r2*7+col]);
                if (vv > mx) { mx = vv; p = r2; }
            }
            if (p != col)
                for (int j = col; j < 7; j++) { const float tt = H[col*7+j]; H[col*7+j] = H[p*7+j]; H[p*7+j] = tt; }
            const float piv = H[col*7+col];
            for (int r2 = col+1; r2 < 6; r2++) {
                const float fct = H[r2*7+col] / piv;
                for (int j = col+1; j < 7; j++) H[r2*7+j] -= fct * H[col*7+j];
            }
        }
        for (int r2 = 5; r2 >= 0; r2--) {
            float s = H[r2*7+6];
            for (int j = r2+1; j < 6; j++) s -= H[r2*7+j] * H[j*7+6];
            H[r2*7+6] = s / H[r2*7+r2];
        }
#pragma unroll
        for (int m = 0; m < MM; m++) alphaS[m] = H[(1+m)*7+6];
        if (t == 0) {                             // publish for k_final
#pragma unroll
            for (int m = 0; m < MM; m++) g_alpha[m] = H[(1+m)*7+6];
            g_lastk = k;
        }
    }
    __syncthreads();

    float al[MM];
#pragma unroll
    for (int m = 0; m < MM; m++) al[m] = alphaS[m];

    // --- pass 1: x~ = bf16(sum_m alpha_m Fm[m]) -> As (no g_xb stream)
#pragma unroll
    for (int i = 0; i < 4; i++) {
        const int e = (i*TPB + tid) * 8;
        const int off = base + e;
        float s[8] = {0,0,0,0,0,0,0,0};
#pragma unroll
        for (int m = 0; m < MM; m++) if (m < nk) {
            short8 fm;
            if (i == 0)      fm = pf0[m];
            else if (i == 1) fm = pf1[m];
            else             fm = *(const short8*)(&g_Fm[m][off]);
#pragma unroll
            for (int j = 0; j < 8; j++)
                s[j] = fmaf(al[m], bf2f((unsigned short)fm[j]), s[j]);
        }
        short8 v;
#pragma unroll
        for (int j = 0; j < 8; j++) v[j] = (short)f2bf(s[j]);
        *(short8*)(As + (e>>9)*PADW + (e&511)) = v;
    }
    __syncthreads();
    // --- pass 2: Fs = bf16(x~ @ lin_w^T + lin_b)
    mfma_gemm<0>(g_Wb, lin_b, As, Fs, nullptr);
    __syncthreads();
    // --- pass 3: state writes + Gram-row dots + residual partials
    float dv[6] = {0,0,0,0,0,0};
    float dself = 0.f;
#pragma unroll
    for (int i = 0; i < 4; i++) {
        const int e = (i*TPB + tid) * 8;
        const int off = base + e, lo = (e>>9)*PADW + (e&511);
        const short8 fv = *(const short8*)(Fs + lo);
        const short8 xv = *(const short8*)(As + lo);
        float gg[8]; short8 gv;
#pragma unroll
        for (int j = 0; j < 8; j++) {
            const float ff = bf2f((unsigned short)fv[j]);
            const float g  = ff - bf2f((unsigned short)xv[j]);
            gg[j] = g; gv[j] = (short)f2bf(g);
            dv[5] = fmaf(ff, ff, dv[5]);
            dself = fmaf(g, g, dself);
        }
        *(short8*)(&g_Fm[idx][off]) = fv;
        *(short8*)(&g_G [idx][off]) = gv;
#pragma unroll
        for (int js = 0; js < MM; js++) {
            if (js != idx && js < nk) {
                const short8 gj = *(const short8*)(&g_G[js][off]);
#pragma unroll
                for (int j = 0; j < 8; j++)
                    dv[js] = fmaf(gg[j], bf2f((unsigned short)gj[j]), dv[js]);
            }
        }
    }
    float vals[6];
#pragma unroll
    for (int j = 0; j < MM; j++) vals[j] = (j == idx) ? (dv[j] + dself) : dv[j];
    vals[5] = dv[5];
    red6(vals, redS, &g_acc[it][b][0]);
}

// ---------------- final: recompute x~last, out = x~ @ weight^T + bias --------
// Bit-identical to k_iter's pass 1 (same fmaf order, same alphas via g_alpha),
// then the MODE-1 GEMM (now float4-vectorized out stores).
__global__ void __launch_bounds__(TPB, 4) k_final(const float* __restrict__ bias,
                                                  float* __restrict__ out)
{
    __shared__ __align__(16) unsigned short As[ROWS*PADW];
    __shared__ float alphaS[MM];
    __shared__ int   nkS;
    const int tid = threadIdx.x;
    const int base = blockIdx.x * (ROWS*FD);

    if (tid == 0) {
        const int lk = g_lastk;
        nkS = (lk < MM) ? lk : MM;
#pragma unroll
        for (int m = 0; m < MM; m++) alphaS[m] = g_alpha[m];
    }
    __syncthreads();
    const int nk = nkS;
    float al[MM];
#pragma unroll
    for (int m = 0; m < MM; m++) al[m] = alphaS[m];

#pragma unroll
    for (int i = 0; i < 4; i++) {
        const int e = (i*TPB + tid) * 8;
        const int off = base + e;
        float s[8] = {0,0,0,0,0,0,0,0};
#pragma unroll
        for (int m = 0; m < MM; m++) if (m < nk) {
            const short8 fm = *(const short8*)(&g_Fm[m][off]);
#pragma unroll
            for (int j = 0; j < 8; j++)
                s[j] = fmaf(al[m], bf2f((unsigned short)fm[j]), s[j]);
        }
        short8 v;
#pragma unroll
        for (int j = 0; j < 8; j++) v[j] = (short)f2bf(s[j]);
        *(short8*)(As + (e>>9)*PADW + (e&511)) = v;
    }
    __syncthreads();
    mfma_gemm<1>(g_WbO, bias, As, nullptr, out + base);
}

extern "C" void kernel_launch(void* const* d_in, const int* in_sizes, int n_in,
                              void* d_out, int out_size, void* d_ws, size_t ws_size,
                              hipStream_t stream)
{
    (void)in_sizes; (void)n_in; (void)out_size; (void)d_ws; (void)ws_size;
    const float* x      = (const float*)d_in[0];
    const float* lin_w  = (const float*)d_in[1];
    const float* lin_b  = (const float*)d_in[2];
    const float* weight = (const float*)d_in[3];
    const float* bias   = (const float*)d_in[4];
    float* out = (float*)d_out;

    hipLaunchKernelGGL(k_init0, dim3(512),  dim3(256), 0, stream, lin_w, weight);
    hipLaunchKernelGGL(k_init1, dim3(NBLK), dim3(TPB), 0, stream, x, lin_b);
    for (int k = 2; k < MAXIT; k++)
        hipLaunchKernelGGL(k_iter, dim3(NBLK), dim3(TPB), 0, stream, lin_b, k);
    hipLaunchKernelGGL(k_final, dim3(NBLK), dim3(TPB), 0, stream, bias, out);
}

// Round 9
// 620.520 us; speedup vs baseline: 1.0164x; 1.0164x over previous
//
#include <hip/hip_runtime.h>
#include <math.h>

#define FD     512
#define NBATCH 16
#define NROWS  16384
#define ROWS   64              // rows per block
#define NBLK   (NROWS/ROWS)    // 256 blocks = 1 per CU
#define TPB    1024            // 16 waves/block
#define MM     5
#define LAMV   1e-4f
#define MAXIT  50
#define TOLV   0.01f
#define NTOT   8388608
#define PADW   520             // LDS row stride (bf16 elems), 16B aligned

typedef __attribute__((ext_vector_type(8))) short  short8;   // 8 bf16
typedef __attribute__((ext_vector_type(4))) short  short4v;  // 4 bf16 (8B)
typedef __attribute__((ext_vector_type(4))) float  float4v;  // MFMA C/D frag

// Persistent device state; fully rewritten (or provably unused) every call.
__device__ unsigned short g_Fm[MM][NTOT];
__device__ unsigned short g_G [MM][NTOT];
__device__ unsigned short g_Wb [FD*FD];        // bf16(lin_w) row-major
__device__ unsigned short g_WbO[FD*FD];        // bf16(weight) row-major
__device__ float g_acc [MAXIT-2][NBATCH][8];   // per-iter Gram-row dots [0..4], ||f||^2 [5]
__device__ float g_acc0[NBATCH][8];            // init dots d00,d01,d11
__device__ float g_alpha[8];                   // alphas of last LIVE iteration
__device__ int   g_lastk;                      // k of last live iteration (>=2)

static __device__ __forceinline__ unsigned short f2bf(float f) {
    unsigned u = __float_as_uint(f);
    u += 0x7fff + ((u >> 16) & 1);             // RNE
    return (unsigned short)(u >> 16);
}
static __device__ __forceinline__ float bf2f(unsigned short s) {
    return __uint_as_float(((unsigned)s) << 16);
}

// 64x512 tile GEMM: D = A(64x512 bf16, LDS) @ W^T + bias, SWAPPED-OPERAND form
// (round-8, proven): mfma(W_frag, A_frag) -> lane holds 4 consecutive output
// cols of one row; epilogue is 8 vector stores. Bit-identical to the original
// orientation (same dot products, same HW reduction tree).
// MODE 0: bf16 -> FsOut (LDS). MODE 1: fp32 -> gout (global tile base).
template<int MODE>
static __device__ __forceinline__ void mfma_gemm(const unsigned short* __restrict__ Wb,
                                                 const float* __restrict__ bvec,
                                                 const unsigned short* AsIn,
                                                 unsigned short* FsOut,
                                                 float* __restrict__ gout)
{
    const int lane = threadIdx.x & 63;
    const int wv   = threadIdx.x >> 6;     // 0..15
    const int lm   = lane & 15;
    const int quad = lane >> 4;
    float4v acc[4][2];
#pragma unroll
    for (int ct = 0; ct < 2; ct++) {
        const int c0 = wv*32 + ct*16 + quad*4;
#pragma unroll
        for (int r = 0; r < 4; r++) {
            const float b = bvec[c0 + r];
#pragma unroll
            for (int r16 = 0; r16 < 4; r16++) acc[r16][ct][r] = b;
        }
    }
#pragma unroll
    for (int q = 0; q < 4; q++) {
#pragma unroll
        for (int kb = 0; kb < 4; kb++) {
            const int ko = q*128 + kb*32 + quad*8;
            short8 bf[2];
#pragma unroll
            for (int ct = 0; ct < 2; ct++)
                bf[ct] = *(const short8*)(Wb + (wv*32 + ct*16 + lm)*FD + ko);
            short8 af[4];
#pragma unroll
            for (int r16 = 0; r16 < 4; r16++)
                af[r16] = *(const short8*)(AsIn + (r16*16 + lm)*PADW + ko);
#pragma unroll
            for (int r16 = 0; r16 < 4; r16++) {
                acc[r16][0] = __builtin_amdgcn_mfma_f32_16x16x32_bf16(bf[0], af[r16], acc[r16][0], 0,0,0);
                acc[r16][1] = __builtin_amdgcn_mfma_f32_16x16x32_bf16(bf[1], af[r16], acc[r16][1], 0,0,0);
            }
        }
    }
#pragma unroll
    for (int ct = 0; ct < 2; ct++) {
        const int c0 = wv*32 + ct*16 + quad*4;
#pragma unroll
        for (int r16 = 0; r16 < 4; r16++) {
            const int row = r16*16 + lm;
            if (MODE == 0) {
                short4v v;
#pragma unroll
                for (int r = 0; r < 4; r++) v[r] = (short)f2bf(acc[r16][ct][r]);
                *(short4v*)(FsOut + row*PADW + c0) = v;
            } else {
                float4 v;
                v.x = acc[r16][ct][0]; v.y = acc[r16][ct][1];
                v.z = acc[r16][ct][2]; v.w = acc[r16][ct][3];
                *(float4*)(gout + row*FD + c0) = v;
            }
        }
    }
}

static __device__ __forceinline__ void red6(const float vals[6], float (*redS)[8], float* accrow)
{
    const int lane = threadIdx.x & 63, wv = threadIdx.x >> 6;   // wv 0..15
#pragma unroll
    for (int j = 0; j < 6; j++) {
        float v = vals[j];
#pragma unroll
        for (int o = 32; o; o >>= 1) v += __shfl_down(v, o);
        if (lane == 0) redS[wv][j] = v;
    }
    __syncthreads();
    if (threadIdx.x < 6) {
        float s = 0.f;
#pragma unroll
        for (int w = 0; w < 16; w++) s += redS[w][threadIdx.x];
        atomicAdd(accrow + threadIdx.x, s);   // device-scope
    }
}

// ---------------- init0: weight bf16 conversion + zero accumulators ----------
__global__ void __launch_bounds__(256) k_init0(const float* __restrict__ lin_w,
                                               const float* __restrict__ weight)
{
    const int i0 = blockIdx.x*256 + threadIdx.x, stride = gridDim.x*256;
    for (int i = i0; i < FD*FD; i += stride) {
        g_Wb [i] = f2bf(lin_w[i]);
        g_WbO[i] = f2bf(weight[i]);
    }
    float* a = &g_acc[0][0][0];
    for (int i = i0; i < (MAXIT-2)*NBATCH*8; i += stride) a[i] = 0.f;
    float* a0 = &g_acc0[0][0];
    for (int i = i0; i < NBATCH*8; i += stride) a0[i] = 0.f;
}

// ---------------- init1: F0=f(x~0), F1=f(F~0), G0, G1, init Gram dots --------
__global__ void __launch_bounds__(TPB, 4) k_init1(const float* __restrict__ x,
                                                  const float* __restrict__ lin_b)
{
    __shared__ __align__(16) unsigned short As[ROWS*PADW];
    __shared__ __align__(16) unsigned short Fs[ROWS*PADW];
    __shared__ float redS[16][8];
    const int tid = threadIdx.x;
    const int t = blockIdx.x, b = t >> 4;
    const int base = t * (ROWS*FD);

#pragma unroll
    for (int i = 0; i < 4; i++) {               // bf16(x0 tile) -> As
        const int e = (i*TPB + tid) * 8;
        const float4 a0 = *(const float4*)(x + base + e);
        const float4 a1 = *(const float4*)(x + base + e + 4);
        short8 v;
        v[0]=f2bf(a0.x); v[1]=f2bf(a0.y); v[2]=f2bf(a0.z); v[3]=f2bf(a0.w);
        v[4]=f2bf(a1.x); v[5]=f2bf(a1.y); v[6]=f2bf(a1.z); v[7]=f2bf(a1.w);
        *(short8*)(As + (e>>9)*PADW + (e&511)) = v;
    }
    __syncthreads();
    mfma_gemm<0>(g_Wb, lin_b, As, Fs, nullptr);   // Fs = bf16(f(x~0))
    __syncthreads();
    float d00 = 0.f;
#pragma unroll
    for (int i = 0; i < 4; i++) {
        const int e = (i*TPB + tid) * 8;
        const int off = base + e, lo = (e>>9)*PADW + (e&511);
        const short8 fv = *(const short8*)(Fs + lo);
        const short8 xv = *(const short8*)(As + lo);
        short8 gv;
#pragma unroll
        for (int j = 0; j < 8; j++) {
            const float g = bf2f((unsigned short)fv[j]) - bf2f((unsigned short)xv[j]);
            gv[j] = (short)f2bf(g);
            d00 = fmaf(g, g, d00);
        }
        *(short8*)(&g_Fm[0][off]) = fv;
        *(short8*)(&g_G [0][off]) = gv;
    }
    __syncthreads();
    mfma_gemm<0>(g_Wb, lin_b, Fs, As, nullptr);   // As = bf16(f(F~0))
    __syncthreads();
    float d01 = 0.f, d11 = 0.f;
#pragma unroll
    for (int i = 0; i < 4; i++) {
        const int e = (i*TPB + tid) * 8;
        const int off = base + e, lo = (e>>9)*PADW + (e&511);
        const short8 f1 = *(const short8*)(As + lo);
        const short8 f0 = *(const short8*)(Fs + lo);
        const short8 g0 = *(const short8*)(&g_G[0][off]);
        short8 gv;
#pragma unroll
        for (int j = 0; j < 8; j++) {
            const float g = bf2f((unsigned short)f1[j]) - bf2f((unsigned short)f0[j]);
            gv[j] = (short)f2bf(g);
            d11 = fmaf(g, g, d11);
            d01 = fmaf(bf2f((unsigned short)g0[j]), g, d01);
        }
        *(short8*)(&g_Fm[1][off]) = f1;
        *(short8*)(&g_G [1][off]) = gv;
    }
    const float vals[6] = {d00, d01, d11, 0.f, 0.f, 0.f};
    red6(vals, redS, &g_acc0[b][0]);
}

// ---------------- one Anderson iteration (k = 2..49) -------------------------
__global__ void __launch_bounds__(TPB, 4) k_iter(const float* __restrict__ lin_b, int k)
{
    __shared__ __align__(16) unsigned short As[ROWS*PADW];
    __shared__ __align__(16) unsigned short Fs[ROWS*PADW];
    __shared__ float gramS[MM][MM];
    __shared__ float alphaS[MM];
    __shared__ float Hs[48];
    __shared__ float redS[16][8];
    __shared__ float gAs[MM][MM];   // Gram window cache (wave-1 parallel load)
    __shared__ float ga0S[3];       // d00,d01,d11
    __shared__ float sres;

    const int tid = threadIdx.x;
    const int t = blockIdx.x, b = t >> 4;
    const int base = t * (ROWS*FD);
    const int it = k - 2, idx = k % MM, nk = (k < MM) ? k : MM;
    const int j0 = (k - 5 > 2) ? (k - 5) : 2;

    // wave 0: residual of iteration k-1 (skipped iterations leave zeros)
    if (k > 2 && (tid >> 6) == 0) {
        float v = 0.f;
        if (tid < 32) {
            const int bb = tid & 15;
            const int jj = (tid < 16) ? ((k-1) % MM) : 5;
            v = g_acc[it-1][bb][jj];
        }
        v += __shfl_xor(v, 1); v += __shfl_xor(v, 2);
        v += __shfl_xor(v, 4); v += __shfl_xor(v, 8);
        const float num = __shfl(v, 0), den = __shfl(v, 16);
        if (tid == 0) sres = sqrtf(num) / (1e-5f + sqrtf(den));
    }
    // wave 1: Gram window + init dots -> LDS (kills ~25 serialized lane-0 loads)
    if ((tid >> 6) == 1) {
        const int l = tid & 63;
        if (l < 25) {
            const int jj = j0 + l/5;
            if (jj < k) gAs[l/5][l%5] = g_acc[jj-2][b][l%5];
        } else if (l < 28) {
            ga0S[l-25] = g_acc0[b][l-25];
        }
    }
    __syncthreads();
    if (k > 2 && sres < TOLV) return;            // uniform across grid
    // NOTE: dead launches return HERE with only the tiny residual/Gram loads
    // in flight (~2.5 us). ALL bulk prefetches must stay AFTER this gate
    // (round-5 regression: pre-gate prefetch cost +~280 us across dead launches).

    // Prefetch pass-1 Fm reads, chunks 0-1 (own tile). Issued by all waves
    // before lane 0's serial solve, so the ~2-4 us solve hides the latency.
    short8 pf0[MM], pf1[MM];
#pragma unroll
    for (int m = 0; m < MM; m++) if (m < nk) {
        pf0[m] = *(const short8*)(&g_Fm[m][base + (0*TPB + tid)*8]);
        pf1[m] = *(const short8*)(&g_Fm[m][base + (1*TPB + tid)*8]);
    }
    __builtin_amdgcn_sched_barrier(0);           // keep loads above the solve

    // --- Gram replay (chronological, last <=5 iterations) + bordered 6x6 solve
    if (tid == 0) {
#pragma unroll
        for (int i = 0; i < MM; i++)
#pragma unroll
            for (int j = 0; j < MM; j++) gramS[i][j] = 0.f;
        gramS[0][0] = ga0S[0];
        gramS[0][1] = gramS[1][0] = ga0S[1];
        gramS[1][1] = ga0S[2];
        for (int j = j0; j < k; j++) {
            const int ij = j % MM, nkj = (j < MM) ? j : MM;
            for (int c = 0; c < MM; c++)
                if (c < nkj || c == ij) {
                    const float vv = gAs[j - j0][c];
                    gramS[ij][c] = vv; gramS[c][ij] = vv;
                }
        }
        float* H = Hs;                            // 6x7 augmented
        for (int i = 0; i < 42; i++) H[i] = 0.f;
        for (int j = 0; j < nk; j++) { H[1+j] = 1.f; H[(1+j)*7] = 1.f; }
#pragma unroll
        for (int i = 0; i < MM; i++) H[(1+i)*7 + (1+i)] = LAMV;
        for (int i = 0; i < nk; i++)
            for (int j = 0; j < nk; j++)
                H[(1+i)*7 + (1+j)] = gramS[i][j] + (i == j ? LAMV : 0.f);
        H[6] = 1.f;                               // rhs = e0
        for (int col = 0; col < 6; col++) {
            int p = col; float mx = fabsf(H[col*7+col]);
            for (int r2 = col+1; r2 < 6; r2++) {
                const float vv = fabsf(H[r2*7+col]);
                if (vv > mx) { mx = vv; p = r2; }
            }
            if (p != col)
                for (int j = col; j < 7; j++) { const float tt = H[col*7+j]; H[col*7+j] = H[p*7+j]; H[p*7+j] = tt; }
            const float piv = H[col*7+col];
            for (int r2 = col+1; r2 < 6; r2++) {
                const float fct = H[r2*7+col] / piv;
                for (int j = col+1; j < 7; j++) H[r2*7+j] -= fct * H[col*7+j];
            }
        }
        for (int r2 = 5; r2 >= 0; r2--) {
            float s = H[r2*7+6];
            for (int j = r2+1; j < 6; j++) s -= H[r2*7+j] * H[j*7+6];
            H[r2*7+6] = s / H[r2*7+r2];
        }
#pragma unroll
        for (int m = 0; m < MM; m++) alphaS[m] = H[(1+m)*7+6];
        if (t == 0) {                             // publish for k_final
#pragma unroll
            for (int m = 0; m < MM; m++) g_alpha[m] = H[(1+m)*7+6];
            g_lastk = k;
        }
    }
    __syncthreads();

    float al[MM];
#pragma unroll
    for (int m = 0; m < MM; m++) al[m] = alphaS[m];

    // --- pass 1: x~ = bf16(sum_m alpha_m Fm[m]) -> As (no g_xb stream)
#pragma unroll
    for (int i = 0; i < 4; i++) {
        const int e = (i*TPB + tid) * 8;
        const int off = base + e;
        float s[8] = {0,0,0,0,0,0,0,0};
#pragma unroll
        for (int m = 0; m < MM; m++) if (m < nk) {
            short8 fm;
            if (i == 0)      fm = pf0[m];
            else if (i == 1) fm = pf1[m];
            else             fm = *(const short8*)(&g_Fm[m][off]);
#pragma unroll
            for (int j = 0; j < 8; j++)
                s[j] = fmaf(al[m], bf2f((unsigned short)fm[j]), s[j]);
        }
        short8 v;
#pragma unroll
        for (int j = 0; j < 8; j++) v[j] = (short)f2bf(s[j]);
        *(short8*)(As + (e>>9)*PADW + (e&511)) = v;
    }
    __syncthreads();

    // --- G-slot prefetch, chunks 0-1: the old G[js] (js != idx) do NOT depend
    // on the GEMM output, so issue their loads now. The ~5 us GEMM (MFMA +
    // L2 W-reads) hides the L3 latency; the post-GEMM barrier's vmcnt drain
    // lands after they are long complete. +32 VGPRs, lifetimes disjoint from
    // pf0/pf1 (consumed above), peak stays under the 128-VGPR occupancy cliff.
    short8 gpf0[MM], gpf1[MM];
#pragma unroll
    for (int js = 0; js < MM; js++) if (js != idx && js < nk) {
        gpf0[js] = *(const short8*)(&g_G[js][base + (0*TPB + tid)*8]);
        gpf1[js] = *(const short8*)(&g_G[js][base + (1*TPB + tid)*8]);
    }
    __builtin_amdgcn_sched_barrier(0);           // keep loads above the GEMM

    // --- pass 2: Fs = bf16(x~ @ lin_w^T + lin_b)
    mfma_gemm<0>(g_Wb, lin_b, As, Fs, nullptr);
    __syncthreads();
    // --- pass 3: state writes + Gram-row dots + residual partials
    float dv[6] = {0,0,0,0,0,0};
    float dself = 0.f;
#pragma unroll
    for (int i = 0; i < 4; i++) {
        const int e = (i*TPB + tid) * 8;
        const int off = base + e, lo = (e>>9)*PADW + (e&511);
        const short8 fv = *(const short8*)(Fs + lo);
        const short8 xv = *(const short8*)(As + lo);
        float gg[8]; short8 gv;
#pragma unroll
        for (int j = 0; j < 8; j++) {
            const float ff = bf2f((unsigned short)fv[j]);
            const float g  = ff - bf2f((unsigned short)xv[j]);
            gg[j] = g; gv[j] = (short)f2bf(g);
            dv[5] = fmaf(ff, ff, dv[5]);
            dself = fmaf(g, g, dself);
        }
        *(short8*)(&g_Fm[idx][off]) = fv;
        *(short8*)(&g_G [idx][off]) = gv;
#pragma unroll
        for (int js = 0; js < MM; js++) {
            if (js != idx && js < nk) {
                short8 gj;
                if (i == 0)      gj = gpf0[js];
                else if (i == 1) gj = gpf1[js];
                else             gj = *(const short8*)(&g_G[js][off]);
#pragma unroll
                for (int j = 0; j < 8; j++)
                    dv[js] = fmaf(gg[j], bf2f((unsigned short)gj[j]), dv[js]);
            }
        }
    }
    float vals[6];
#pragma unroll
    for (int j = 0; j < MM; j++) vals[j] = (j == idx) ? (dv[j] + dself) : dv[j];
    vals[5] = dv[5];
    red6(vals, redS, &g_acc[it][b][0]);
}

// ---------------- final: recompute x~last, out = x~ @ weight^T + bias --------
// Bit-identical to k_iter's pass 1 (same fmaf order, same alphas via g_alpha),
// then the MODE-1 GEMM (float4-vectorized out stores). Fm chunks 0-1 are
// prefetched before the alpha/barrier section (addresses are nk-independent;
// use is guarded by m<nk, so stale slots never feed the arithmetic).
__global__ void __launch_bounds__(TPB, 4) k_final(const float* __restrict__ bias,
                                                  float* __restrict__ out)
{
    __shared__ __align__(16) unsigned short As[ROWS*PADW];
    __shared__ float alphaS[MM];
    __shared__ int   nkS;
    const int tid = threadIdx.x;
    const int base = blockIdx.x * (ROWS*FD);

    short8 pf0[MM], pf1[MM];
#pragma unroll
    for (int m = 0; m < MM; m++) {
        pf0[m] = *(const short8*)(&g_Fm[m][base + (0*TPB + tid)*8]);
        pf1[m] = *(const short8*)(&g_Fm[m][base + (1*TPB + tid)*8]);
    }
    __builtin_amdgcn_sched_barrier(0);

    if (tid == 0) {
        const int lk = g_lastk;
        nkS = (lk < MM) ? lk : MM;
#pragma unroll
        for (int m = 0; m < MM; m++) alphaS[m] = g_alpha[m];
    }
    __syncthreads();
    const int nk = nkS;
    float al[MM];
#pragma unroll
    for (int m = 0; m < MM; m++) al[m] = alphaS[m];

#pragma unroll
    for (int i = 0; i < 4; i++) {
        const int e = (i*TPB + tid) * 8;
        const int off = base + e;
        float s[8] = {0,0,0,0,0,0,0,0};
#pragma unroll
        for (int m = 0; m < MM; m++) if (m < nk) {
            short8 fm;
            if (i == 0)      fm = pf0[m];
            else if (i == 1) fm = pf1[m];
            else             fm = *(const short8*)(&g_Fm[m][off]);
#pragma unroll
            for (int j = 0; j < 8; j++)
                s[j] = fmaf(al[m], bf2f((unsigned short)fm[j]), s[j]);
        }
        short8 v;
#pragma unroll
        for (int j = 0; j < 8; j++) v[j] = (short)f2bf(s[j]);
        *(short8*)(As + (e>>9)*PADW + (e&511)) = v;
    }
    __syncthreads();
    mfma_gemm<1>(g_WbO, bias, As, nullptr, out + base);
}

extern "C" void kernel_launch(void* const* d_in, const int* in_sizes, int n_in,
                              void* d_out, int out_size, void* d_ws, size_t ws_size,
                              hipStream_t stream)
{
    (void)in_sizes; (void)n_in; (void)out_size; (void)d_ws; (void)ws_size;
    const float* x      = (const float*)d_in[0];
    const float* lin_w  = (const float*)d_in[1];
    const float* lin_b  = (const float*)d_in[2];
    const float* weight = (const float*)d_in[3];
    const float* bias   = (const float*)d_in[4];
    float* out = (float*)d_out;

    hipLaunchKernelGGL(k_init0, dim3(512),  dim3(256), 0, stream, lin_w, weight);
    hipLaunchKernelGGL(k_init1, dim3(NBLK), dim3(TPB), 0, stream, x, lin_b);
    for (int k = 2; k < MAXIT; k++)
        hipLaunchKernelGGL(k_iter, dim3(NBLK), dim3(TPB), 0, stream, lin_b, k);
    hipLaunchKernelGGL(k_final, dim3(NBLK), dim3(TPB), 0, stream, bias, out);
}